// Round 9
// baseline (130.414 us; speedup 1.0000x reference)
//
#include <hip/hip_runtime.h>
#include <hip/hip_fp16.h>

// out[n,c] = sum_{e: dst[e]==n} ( sum_k x[src[e],k]*W3[k]*x[dst[e],k] ) * x[src[e],c] * W2[c]
// B=1, N=100000, E=1600000, C=128.
//
// Pipeline (5 launches, no global atomic-returns anywhere):
//   k_pack_hist : fused; x fp32->fp16 pack blocks + per-block coarse-bin
//                 histogram blocks (bin = dst>>5)
//   k_pscan1/2  : exclusive scan of bin-major (bin,block) counts;
//                 R9: LDS-tiled transpose -> coalesced reads of hist_bm
//   k_place     : deterministic placement of packed (dstlow|src) into bins
//   k_sort_accum: per-bin LDS counting sort by dstlow + fused accumulation.
//                 R9: per-wave sort counters (4x fewer LDS-atomic conflicts),
//                 8/4/1 gather ladder per 16-lane group, dst-row prefetch
//                 hidden under the sort.
// Fallback: R1-style pure-atomic kernel if constraints unmet.

#define CCH 128
#define BSHIFT 5
#define BWIDTH 32              // nodes per bin
#define MAXBIN 4096            // supports N <= 131072 (17-bit src pack)
#define CH 8192                // edges per partition block
#define LDSCAP 1280            // max edges staged per bin (mean ~512)
#define TBINS 16               // bins per pscan1 block
#define NBLKCAP 256            // max partition blocks supported by pscan1 tile

// ---------------- fused fp16 pack + per-block bin histogram ----------------

__global__ __launch_bounds__(256) void k_pack_hist(
    const float* __restrict__ x, __half* __restrict__ xh, int n4, int nPack,
    const int* __restrict__ dst, int E, int NBIN, int* __restrict__ hist_bm)
{
    __shared__ int cnt[MAXBIN];
    const int tid = threadIdx.x;

    if (blockIdx.x < nPack) {                 // pack role
        const int i = blockIdx.x * 256 + tid;
        if (i < n4) {
            float4 v = reinterpret_cast<const float4*>(x)[i];
            __half2* o = reinterpret_cast<__half2*>(xh) + (size_t)i * 2;
            o[0] = __floats2half2_rn(v.x, v.y);
            o[1] = __floats2half2_rn(v.z, v.w);
        }
        return;
    }

    const int blk = blockIdx.x - nPack;       // histogram role
    for (int b = tid; b < NBIN; b += 256) cnt[b] = 0;
    __syncthreads();

    const int e0 = blk * CH;
    #pragma unroll
    for (int k = 0; k < CH / 1024; ++k) {
        const int g = (e0 >> 2) + k * 256 + tid;   // int4 index
        const int e = g << 2;
        if (e >= E) continue;
        if (e + 4 <= E) {
            const int4 d4 = reinterpret_cast<const int4*>(dst)[g];
            atomicAdd(&cnt[d4.x >> BSHIFT], 1);
            atomicAdd(&cnt[d4.y >> BSHIFT], 1);
            atomicAdd(&cnt[d4.z >> BSHIFT], 1);
            atomicAdd(&cnt[d4.w >> BSHIFT], 1);
        } else {
            for (int ee = e; ee < E; ++ee) atomicAdd(&cnt[dst[ee] >> BSHIFT], 1);
        }
    }
    __syncthreads();
    int* hb = hist_bm + (size_t)blk * NBIN;   // block-major, coalesced writes
    for (int b = tid; b < NBIN; b += 256) hb[b] = cnt[b];
}

// ---------------- scan: LDS-tiled transpose, coalesced reads ----------------
// Block handles TBINS consecutive bins; loads hist_bm[blk][bin] tile with
// coalesced 64B reads, scans bin-major from LDS.

__global__ __launch_bounds__(256) void k_pscan1(
    const int* __restrict__ hist_bm, int NBIN, int NBLK,
    int* __restrict__ partial, int* __restrict__ blocksum)
{
    __shared__ int tile[TBINS][NBLKCAP + 1];
    __shared__ int sdata[256];
    const int t = threadIdx.x;
    const int B0 = blockIdx.x * TBINS;

    for (int g = t; g < TBINS * (NBLKCAP + 1); g += 256)
        (&tile[0][0])[g] = 0;
    __syncthreads();

    for (int g = t; g < NBLK * TBINS; g += 256) {
        const int blk = g >> 4;               // g / TBINS
        const int tb  = g & (TBINS - 1);
        const int bin = B0 + tb;
        if (bin < NBIN) tile[tb][blk] = hist_bm[(size_t)blk * NBIN + bin];
    }
    __syncthreads();

    // thread t covers padded-flat [t*16, t*16+16): row tb = t>>4, blk bk0..bk0+15
    const int tb  = t >> 4;
    const int bk0 = (t & 15) * 16;
    int v[16];
    int local = 0;
    #pragma unroll
    for (int k = 0; k < 16; ++k) { v[k] = tile[tb][bk0 + k]; local += v[k]; }

    sdata[t] = local;
    __syncthreads();
    #pragma unroll
    for (int off = 1; off < 256; off <<= 1) {
        int val = (t >= off) ? sdata[t - off] : 0;
        __syncthreads();
        sdata[t] += val;
        __syncthreads();
    }
    const int incl = sdata[t];
    int run = incl - local;
    if (t == 255) blocksum[blockIdx.x] = incl;

    const int bin = B0 + tb;
    if (bin < NBIN) {
        #pragma unroll
        for (int k = 0; k < 16; ++k) {
            const int blk = bk0 + k;
            if (blk < NBLK) partial[(size_t)bin * NBLK + blk] = run;
            run += v[k];
        }
    }
}

__global__ void k_scan2(int* __restrict__ blocksum, int nb) {
    __shared__ int sdata[1024];
    const int t = threadIdx.x;
    const int v = (t < nb) ? blocksum[t] : 0;
    sdata[t] = v;
    __syncthreads();
    for (int off = 1; off < 1024; off <<= 1) {
        int val = (t >= off) ? sdata[t - off] : 0;
        __syncthreads();
        sdata[t] += val;
        __syncthreads();
    }
    if (t < nb) blocksum[t] = sdata[t] - v;
}

// ---------------- deterministic placement ----------------

__global__ __launch_bounds__(256) void k_place(
    const int* __restrict__ src, const int* __restrict__ dst, int E, int NBIN, int NBLK,
    const int* __restrict__ partial, const int* __restrict__ blocksum,
    unsigned int* __restrict__ coarse)
{
    __shared__ int lcur[MAXBIN];
    const int blk = blockIdx.x;
    const int tid = threadIdx.x;
    for (int b = tid; b < NBIN; b += 256) {
        lcur[b] = partial[(size_t)b * NBLK + blk] + blocksum[b / TBINS];
    }
    __syncthreads();

    const int e0 = blk * CH;
    #pragma unroll
    for (int k = 0; k < CH / 1024; ++k) {
        const int g = (e0 >> 2) + k * 256 + tid;
        const int e = g << 2;
        if (e >= E) continue;
        if (e + 4 <= E) {
            const int4 d4 = reinterpret_cast<const int4*>(dst)[g];
            const int4 s4 = reinterpret_cast<const int4*>(src)[g];
            int p;
            p = atomicAdd(&lcur[d4.x >> BSHIFT], 1);
            coarse[p] = (unsigned)s4.x | ((unsigned)(d4.x & (BWIDTH - 1)) << 17);
            p = atomicAdd(&lcur[d4.y >> BSHIFT], 1);
            coarse[p] = (unsigned)s4.y | ((unsigned)(d4.y & (BWIDTH - 1)) << 17);
            p = atomicAdd(&lcur[d4.z >> BSHIFT], 1);
            coarse[p] = (unsigned)s4.z | ((unsigned)(d4.z & (BWIDTH - 1)) << 17);
            p = atomicAdd(&lcur[d4.w >> BSHIFT], 1);
            coarse[p] = (unsigned)s4.w | ((unsigned)(d4.w & (BWIDTH - 1)) << 17);
        } else {
            for (int ee = e; ee < E; ++ee) {
                const int d = dst[ee], s = src[ee];
                int p = atomicAdd(&lcur[d >> BSHIFT], 1);
                coarse[p] = (unsigned)s | ((unsigned)(d & (BWIDTH - 1)) << 17);
            }
        }
    }
}

// ---------------- per-bin LDS counting sort + fused accumulation ----------------
// 16 groups of 16 lanes; group gid owns nodes gid*2, gid*2+1. Lane sl owns
// channels sl*8..sl*8+7 (16B fp16 loads). Per-wave sort counters; 8/4/1
// gather ladder; dst rows prefetched before the sort barriers.

__global__ __launch_bounds__(256, 2) void k_sort_accum(
    const __half* __restrict__ xh,
    const float* __restrict__ W2,
    const float* __restrict__ W3,
    const unsigned int* __restrict__ coarse,
    const int* __restrict__ partial, const int* __restrict__ blocksum,
    int NBIN, int NBLK, int E, int N,
    float* __restrict__ out)
{
    __shared__ unsigned int raw[LDSCAP];
    __shared__ int srcl[LDSCAP];
    __shared__ int cnt4[4][BWIDTH];
    __shared__ int cur4[4][BWIDTH];
    __shared__ int offs[BWIDTH], cnt[BWIDTH];

    const int bin  = blockIdx.x;
    const int tid  = threadIdx.x;
    const int wv   = tid >> 6;
    const int lane = tid & 63;
    const int grp  = lane >> 4;
    const int sl   = lane & 15;
    const int gid  = wv * 4 + grp;
    const int choff = sl << 4;
    const char* xb = (const char*)xh;

    union H { int4 i4; __half2 h[4]; };

    // prefetch this group's two dst rows (latency hidden under the sort)
    const int node0 = (bin << BSHIFT) + gid * 2;
    const int node1 = node0 + 1;
    H uD0, uD1;
    uD0.i4 = make_int4(0, 0, 0, 0);
    uD1.i4 = make_int4(0, 0, 0, 0);
    if (node0 < N) uD0.i4 = *reinterpret_cast<const int4*>(xb + (((size_t)node0) << 8) + choff);
    if (node1 < N) uD1.i4 = *reinterpret_cast<const int4*>(xb + (((size_t)node1) << 8) + choff);

    const size_t i0 = (size_t)bin * NBLK;
    const int beg = partial[i0] + blocksum[bin / TBINS];
    const int end = (bin + 1 < NBIN)
        ? partial[i0 + NBLK] + blocksum[(bin + 1) / TBINS] : E;
    const int mtot = end - beg;
    const int m = (mtot < LDSCAP) ? mtot : LDSCAP;

    if (tid < 4 * BWIDTH) (&cnt4[0][0])[tid] = 0;
    __syncthreads();

    for (int i = tid; i < m; i += 256) {
        unsigned u = coarse[beg + i];
        raw[i] = u;
        atomicAdd(&cnt4[wv][u >> 17], 1);     // per-wave counters
    }
    __syncthreads();

    if (tid < BWIDTH) {                       // lanes 0..31 of wave 0
        const int c0 = cnt4[0][tid], c1 = cnt4[1][tid];
        const int c2 = cnt4[2][tid], c3 = cnt4[3][tid];
        const int tot = c0 + c1 + c2 + c3;
        int v = tot;
        #pragma unroll
        for (int d2 = 1; d2 < BWIDTH; d2 <<= 1) {
            int t2 = __shfl_up(v, d2, 64);
            if (tid >= d2) v += t2;
        }
        const int ex = v - tot;
        offs[tid] = ex;
        cnt[tid]  = tot;
        cur4[0][tid] = ex;
        cur4[1][tid] = ex + c0;
        cur4[2][tid] = ex + c0 + c1;
        cur4[3][tid] = ex + c0 + c1 + c2;
    }
    __syncthreads();

    for (int i = tid; i < m; i += 256) {
        const unsigned u = raw[i];
        const int p = atomicAdd(&cur4[wv][u >> 17], 1);   // own wave's cursor
        srcl[p] = (int)(u & 0x1FFFFu);
    }
    __syncthreads();

    const float4 w3a = *reinterpret_cast<const float4*>(W3 + sl * 8);
    const float4 w3b = *reinterpret_cast<const float4*>(W3 + sl * 8 + 4);
    const float4 w2a = *reinterpret_cast<const float4*>(W2 + sl * 8);
    const float4 w2b = *reinterpret_cast<const float4*>(W2 + sl * 8 + 4);

    #pragma unroll
    for (int i = 0; i < 2; ++i) {
        const int node = (i == 0) ? node0 : node1;
        if (node >= N) continue;
        const int dl = gid * 2 + i;
        const H uD = (i == 0) ? uD0 : uD1;

        const float2 e0 = __half22float2(uD.h[0]);
        const float2 e1 = __half22float2(uD.h[1]);
        const float2 e2 = __half22float2(uD.h[2]);
        const float2 e3 = __half22float2(uD.h[3]);
        const float4 va = make_float4(w3a.x * e0.x, w3a.y * e0.y,
                                      w3a.z * e1.x, w3a.w * e1.y);
        const float4 vb = make_float4(w3b.x * e2.x, w3b.y * e2.y,
                                      w3b.z * e3.x, w3b.w * e3.y);

        float4 accA = make_float4(0.f, 0.f, 0.f, 0.f);
        float4 accB = make_float4(0.f, 0.f, 0.f, 0.f);

        const int b0 = offs[dl];
        const int c  = cnt[dl];

        int j = 0;
        for (; j + 8 <= c; j += 8) {          // 8 gathers in flight per group
            H q[8];
            #pragma unroll
            for (int k = 0; k < 8; ++k)
                q[k].i4 = *reinterpret_cast<const int4*>(
                    xb + (((size_t)srcl[b0 + j + k]) << 8) + choff);
            float2 f0[8], f1[8], f2[8], f3[8];
            float p[8];
            #pragma unroll
            for (int k = 0; k < 8; ++k) {
                f0[k] = __half22float2(q[k].h[0]);
                f1[k] = __half22float2(q[k].h[1]);
                f2[k] = __half22float2(q[k].h[2]);
                f3[k] = __half22float2(q[k].h[3]);
                p[k] = f0[k].x * va.x + f0[k].y * va.y + f1[k].x * va.z + f1[k].y * va.w
                     + f2[k].x * vb.x + f2[k].y * vb.y + f3[k].x * vb.z + f3[k].y * vb.w;
            }
            #pragma unroll
            for (int off = 1; off < 16; off <<= 1) {
                #pragma unroll
                for (int k = 0; k < 8; ++k) p[k] += __shfl_xor(p[k], off, 64);
            }
            #pragma unroll
            for (int k = 0; k < 8; ++k) {
                accA.x += p[k] * f0[k].x; accA.y += p[k] * f0[k].y;
                accA.z += p[k] * f1[k].x; accA.w += p[k] * f1[k].y;
                accB.x += p[k] * f2[k].x; accB.y += p[k] * f2[k].y;
                accB.z += p[k] * f3[k].x; accB.w += p[k] * f3[k].y;
            }
        }
        for (; j + 4 <= c; j += 4) {
            H q[4];
            #pragma unroll
            for (int k = 0; k < 4; ++k)
                q[k].i4 = *reinterpret_cast<const int4*>(
                    xb + (((size_t)srcl[b0 + j + k]) << 8) + choff);
            float2 f0[4], f1[4], f2[4], f3[4];
            float p[4];
            #pragma unroll
            for (int k = 0; k < 4; ++k) {
                f0[k] = __half22float2(q[k].h[0]);
                f1[k] = __half22float2(q[k].h[1]);
                f2[k] = __half22float2(q[k].h[2]);
                f3[k] = __half22float2(q[k].h[3]);
                p[k] = f0[k].x * va.x + f0[k].y * va.y + f1[k].x * va.z + f1[k].y * va.w
                     + f2[k].x * vb.x + f2[k].y * vb.y + f3[k].x * vb.z + f3[k].y * vb.w;
            }
            #pragma unroll
            for (int off = 1; off < 16; off <<= 1) {
                #pragma unroll
                for (int k = 0; k < 4; ++k) p[k] += __shfl_xor(p[k], off, 64);
            }
            #pragma unroll
            for (int k = 0; k < 4; ++k) {
                accA.x += p[k] * f0[k].x; accA.y += p[k] * f0[k].y;
                accA.z += p[k] * f1[k].x; accA.w += p[k] * f1[k].y;
                accB.x += p[k] * f2[k].x; accB.y += p[k] * f2[k].y;
                accB.z += p[k] * f3[k].x; accB.w += p[k] * f3[k].y;
            }
        }
        for (; j < c; ++j) {
            H u0;
            u0.i4 = *reinterpret_cast<const int4*>(
                xb + (((size_t)srcl[b0 + j]) << 8) + choff);
            const float2 f0 = __half22float2(u0.h[0]);
            const float2 f1 = __half22float2(u0.h[1]);
            const float2 f2 = __half22float2(u0.h[2]);
            const float2 f3 = __half22float2(u0.h[3]);
            float p = f0.x * va.x + f0.y * va.y + f1.x * va.z + f1.y * va.w
                    + f2.x * vb.x + f2.y * vb.y + f3.x * vb.z + f3.y * vb.w;
            #pragma unroll
            for (int off = 1; off < 16; off <<= 1) p += __shfl_xor(p, off, 64);
            accA.x += p * f0.x; accA.y += p * f0.y;
            accA.z += p * f1.x; accA.w += p * f1.y;
            accB.x += p * f2.x; accB.y += p * f2.y;
            accB.z += p * f3.x; accB.w += p * f3.y;
        }
        // LDS-capacity overflow (normally zero iterations)
        for (int i2 = LDSCAP; i2 < mtot; ++i2) {
            const unsigned u = coarse[beg + i2];
            if ((int)(u >> 17) != dl) continue;
            H u0;
            u0.i4 = *reinterpret_cast<const int4*>(
                xb + (((size_t)(u & 0x1FFFFu)) << 8) + choff);
            const float2 f0 = __half22float2(u0.h[0]);
            const float2 f1 = __half22float2(u0.h[1]);
            const float2 f2 = __half22float2(u0.h[2]);
            const float2 f3 = __half22float2(u0.h[3]);
            float p = f0.x * va.x + f0.y * va.y + f1.x * va.z + f1.y * va.w
                    + f2.x * vb.x + f2.y * vb.y + f3.x * vb.z + f3.y * vb.w;
            #pragma unroll
            for (int off = 1; off < 16; off <<= 1) p += __shfl_xor(p, off, 64);
            accA.x += p * f0.x; accA.y += p * f0.y;
            accA.z += p * f1.x; accA.w += p * f1.y;
            accB.x += p * f2.x; accB.y += p * f2.y;
            accB.z += p * f3.x; accB.w += p * f3.y;
        }

        accA.x *= w2a.x; accA.y *= w2a.y; accA.z *= w2a.z; accA.w *= w2a.w;
        accB.x *= w2b.x; accB.y *= w2b.y; accB.z *= w2b.z; accB.w *= w2b.w;
        float* orow = out + (size_t)node * CCH + sl * 8;
        *reinterpret_cast<float4*>(orow)     = accA;
        *reinterpret_cast<float4*>(orow + 4) = accB;
    }
}

// ---------------- last-resort fallback: pure fp32 atomics (R1) ----------------

__global__ __launch_bounds__(256) void edge_gather_scatter(
    const float* __restrict__ x, const int* __restrict__ edge_index,
    const float* __restrict__ W2, const float* __restrict__ W3,
    float* __restrict__ out, int E)
{
    const int e    = (blockIdx.x * blockDim.x + threadIdx.x) >> 6;
    const int lane = threadIdx.x & 63;
    if (e >= E) return;
    const int s = edge_index[e];
    const int d = edge_index[E + e];
    const float2 xs = *reinterpret_cast<const float2*>(x + (size_t)s * CCH + lane * 2);
    const float2 xd = *reinterpret_cast<const float2*>(x + (size_t)d * CCH + lane * 2);
    const float2 w3 = *reinterpret_cast<const float2*>(W3 + lane * 2);
    const float2 w2 = *reinterpret_cast<const float2*>(W2 + lane * 2);
    float p = xs.x * w3.x * xd.x + xs.y * w3.y * xd.y;
    #pragma unroll
    for (int off = 32; off > 0; off >>= 1) p += __shfl_xor(p, off, 64);
    float* o = out + (size_t)d * CCH + lane * 2;
    atomicAdd(o,     p * xs.x * w2.x);
    atomicAdd(o + 1, p * xs.y * w2.y);
}

// ---------------- launch ----------------

extern "C" void kernel_launch(void* const* d_in, const int* in_sizes, int n_in,
                              void* d_out, int out_size, void* d_ws, size_t ws_size,
                              hipStream_t stream) {
    const float* x          = (const float*)d_in[0];
    const int*   edge_index = (const int*)  d_in[1];
    const float* W2         = (const float*)d_in[2];
    const float* W3         = (const float*)d_in[3];
    float*       out        = (float*)d_out;

    const int E = in_sizes[1] / 2;
    const int N = out_size / CCH;
    const int* src = edge_index;
    const int* dst = edge_index + E;

    const int NBIN = (N + BWIDTH - 1) >> BSHIFT;
    const int NBLK = (E + CH - 1) / CH;
    const long long Mll = (long long)NBIN * NBLK;
    const int M = (int)Mll;
    const int nb1 = (NBIN + TBINS - 1) / TBINS;

    const size_t xh_bytes = (size_t)N * CCH * 2;
    const size_t need = xh_bytes + (size_t)E * 4 + 2 * (size_t)M * 4 + 1024 * 4;

    const bool aligned16 = (((uintptr_t)src & 15) == 0) && (((uintptr_t)dst & 15) == 0);

    if (N <= (1 << 17) && NBIN <= MAXBIN && NBLK <= NBLKCAP && Mll <= (1LL << 20) &&
        nb1 <= 1024 && aligned16 && ws_size >= need) {
        char* base = (char*)d_ws;
        __half* xh       = (__half*)base;        base += xh_bytes;
        unsigned* coarse = (unsigned*)base;      base += (size_t)E * 4;
        int* hist_bm     = (int*)base;           base += (size_t)M * 4;
        int* partial     = (int*)base;           base += (size_t)M * 4;
        int* blocksum    = (int*)base;

        const int n4 = N * CCH / 4;
        const int nPack = (n4 + 255) / 256;

        k_pack_hist<<<nPack + NBLK, 256, 0, stream>>>(x, xh, n4, nPack,
                                                      dst, E, NBIN, hist_bm);
        k_pscan1<<<nb1, 256, 0, stream>>>(hist_bm, NBIN, NBLK, partial, blocksum);
        k_scan2<<<1, 1024, 0, stream>>>(blocksum, nb1);
        k_place<<<NBLK, 256, 0, stream>>>(src, dst, E, NBIN, NBLK,
                                          partial, blocksum, coarse);
        k_sort_accum<<<NBIN, 256, 0, stream>>>(xh, W2, W3, coarse,
                                               partial, blocksum,
                                               NBIN, NBLK, E, N, out);
        return;
    }

    // last resort: pure atomics
    hipMemsetAsync(d_out, 0, (size_t)out_size * sizeof(float), stream);
    const int grid = (E * 64 + 255) / 256;
    edge_gather_scatter<<<grid, 256, 0, stream>>>(x, edge_index, W2, W3, out, E);
}